// Round 6
// baseline (269.814 us; speedup 1.0000x reference)
//
#include <hip/hip_runtime.h>
#include <stdint.h>

typedef unsigned int u32;
typedef _Float16 f16;
typedef f16 half8 __attribute__((ext_vector_type(8)));
typedef float f32x4 __attribute__((ext_vector_type(4)));
typedef uint4 uint4u __attribute__((aligned(4)));   // 4B-aligned vector loads (gfx9+ ok)
typedef uint2 uint2u __attribute__((aligned(4)));
#define TS 4096     // scan tile size (fallback path)
#define KB2 256     // partition buckets per side
#define CH 2048     // entries per phase-A / bhist block

// ---------- bf16 helpers ----------
__device__ __forceinline__ float bflo(u32 u) { return __uint_as_float(u << 16); }
__device__ __forceinline__ float bfhi(u32 u) { return __uint_as_float(u & 0xffff0000u); }
__device__ __forceinline__ u32 f2bf(float x) {
    u32 u = __float_as_uint(x);
    return (u + 0x7fffu + ((u >> 16) & 1u)) >> 16;   // RNE
}
__device__ __forceinline__ u32 pack2(float a, float b) { return f2bf(a) | (f2bf(b) << 16); }

__device__ __forceinline__ int bstart2(int b, int total) {
    return (int)(((unsigned long long)b * (u32)total + KB2 - 1) / KB2);
}

// block-wide exclusive scan, 256 threads, one value per thread
__device__ __forceinline__ int blk_exscan(int v, int& total) {
    __shared__ int ws[5];
    int t = threadIdx.x, lane = t & 63, w = t >> 6;
    int inc = v;
    for (int d = 1; d < 64; d <<= 1) { int u = __shfl_up(inc, d, 64); if (lane >= d) inc += u; }
    __syncthreads();                    // protect ws across repeated calls
    if (lane == 63) ws[w] = inc;
    __syncthreads();
    if (t == 0) { int acc = 0; for (int i = 0; i < 4; ++i) { int x = ws[i]; ws[i] = acc; acc += x; } ws[4] = acc; }
    __syncthreads();
    total = ws[4];
    return ws[w] + (inc - v);
}

// ---------- segment mean core: per-wave, 4 row-slots x 16 chunk-lanes ----------
// Lane-group rs owns a CONTIGUOUS run of items -> one dwordx4 index load feeds 4 gathers.
#define ACC8(v) do { \
    a[0] += bflo((v).x); a[1] += bfhi((v).x); a[2] += bflo((v).y); a[3] += bfhi((v).y); \
    a[4] += bflo((v).z); a[5] += bfhi((v).z); a[6] += bflo((v).w); a[7] += bfhi((v).w); } while (0)

__device__ __forceinline__ void seg_mean8(const u32* __restrict__ in,
                                          const int* __restrict__ items,
                                          const int* __restrict__ off,
                                          int nseg, int nrows, int seg, float a[8]) {
    int lane = threadIdx.x & 63;
    int rs = lane >> 4;
    int cc = lane & 15;
#pragma unroll
    for (int i = 0; i < 8; ++i) a[i] = 0.f;
    int s0 = 0, s1 = 0;
    if (seg < nseg) { s0 = off[seg]; s1 = off[seg + 1]; }
    const uint4* rows = (const uint4*)in;
    int base = s0;
    // 32-wide: 2 vector idx loads + 8 row gathers (8 KB) in flight per wave
    for (; base + 32 <= s1; base += 32) {
        uint4 i0 = *(const uint4u*)&items[base + rs * 4];
        uint4 i1 = *(const uint4u*)&items[base + 16 + rs * 4];
        u32 r0 = i0.x, r1 = i0.y, r2 = i0.z, r3 = i0.w;
        u32 r4 = i1.x, r5 = i1.y, r6 = i1.z, r7 = i1.w;
        r0 = (r0 < (u32)nrows) ? r0 : 0u;  r1 = (r1 < (u32)nrows) ? r1 : 0u;
        r2 = (r2 < (u32)nrows) ? r2 : 0u;  r3 = (r3 < (u32)nrows) ? r3 : 0u;
        r4 = (r4 < (u32)nrows) ? r4 : 0u;  r5 = (r5 < (u32)nrows) ? r5 : 0u;
        r6 = (r6 < (u32)nrows) ? r6 : 0u;  r7 = (r7 < (u32)nrows) ? r7 : 0u;
        uint4 v0 = rows[(size_t)r0 * 16 + cc];
        uint4 v1 = rows[(size_t)r1 * 16 + cc];
        uint4 v2 = rows[(size_t)r2 * 16 + cc];
        uint4 v3 = rows[(size_t)r3 * 16 + cc];
        uint4 v4 = rows[(size_t)r4 * 16 + cc];
        uint4 v5 = rows[(size_t)r5 * 16 + cc];
        uint4 v6 = rows[(size_t)r6 * 16 + cc];
        uint4 v7 = rows[(size_t)r7 * 16 + cc];
        ACC8(v0); ACC8(v1); ACC8(v2); ACC8(v3);
        ACC8(v4); ACC8(v5); ACC8(v6); ACC8(v7);
    }
    // 16-wide: 1 vector idx load + 4 gathers
    for (; base + 16 <= s1; base += 16) {
        uint4 i0 = *(const uint4u*)&items[base + rs * 4];
        u32 r0 = i0.x, r1 = i0.y, r2 = i0.z, r3 = i0.w;
        r0 = (r0 < (u32)nrows) ? r0 : 0u;  r1 = (r1 < (u32)nrows) ? r1 : 0u;
        r2 = (r2 < (u32)nrows) ? r2 : 0u;  r3 = (r3 < (u32)nrows) ? r3 : 0u;
        uint4 v0 = rows[(size_t)r0 * 16 + cc];
        uint4 v1 = rows[(size_t)r1 * 16 + cc];
        uint4 v2 = rows[(size_t)r2 * 16 + cc];
        uint4 v3 = rows[(size_t)r3 * 16 + cc];
        ACC8(v0); ACC8(v1); ACC8(v2); ACC8(v3);
    }
    // 8-wide: 1 uint2 idx load + 2 gathers
    for (; base + 8 <= s1; base += 8) {
        uint2 i0 = *(const uint2u*)&items[base + rs * 2];
        u32 r0 = i0.x, r1 = i0.y;
        r0 = (r0 < (u32)nrows) ? r0 : 0u;
        r1 = (r1 < (u32)nrows) ? r1 : 0u;
        uint4 v0 = rows[(size_t)r0 * 16 + cc];
        uint4 v1 = rows[(size_t)r1 * 16 + cc];
        ACC8(v0); ACC8(v1);
    }
    int idx = base + rs;
    if (idx < s1) {
        u32 r = (u32)items[idx]; r = (r < (u32)nrows) ? r : 0u;
        uint4 v = rows[(size_t)r * 16 + cc];
        ACC8(v);
    }
    idx += 4;
    if (idx < s1) {
        u32 r = (u32)items[idx]; r = (r < (u32)nrows) ? r : 0u;
        uint4 v = rows[(size_t)r * 16 + cc];
        ACC8(v);
    }
#pragma unroll
    for (int i = 0; i < 8; ++i) {
        a[i] += __shfl_xor(a[i], 16, 64);
        a[i] += __shfl_xor(a[i], 32, 64);
    }
    float inv = 1.f / fmaxf((float)(s1 - s0), 1.f);
#pragma unroll
    for (int i = 0; i < 8; ++i) a[i] *= inv;
}

__device__ __forceinline__ void agg4_body(const u32* __restrict__ in,
                                          const int* __restrict__ items,
                                          const int* __restrict__ off,
                                          float* __restrict__ out_f32,
                                          u32* __restrict__ out_bf,
                                          int nseg, int nrows, int do_prelu,
                                          const float* __restrict__ alpha_p, int seg,
                                          int nt) {
    if (seg >= nseg) return;
    int lane = threadIdx.x & 63;
    int rs = lane >> 4;
    int cc = lane & 15;
    float a[8];
    seg_mean8(in, items, off, nseg, nrows, seg, a);
    if (do_prelu) {
        float al = *alpha_p;
#pragma unroll
        for (int i = 0; i < 8; ++i) a[i] = (a[i] >= 0.f) ? a[i] : al * a[i];
    }
    if (rs == 0) {
        if (out_f32) {
            float* o = out_f32 + ((size_t)seg << 7) + cc * 8;
            f32x4 v0 = {a[0], a[1], a[2], a[3]};
            f32x4 v1 = {a[4], a[5], a[6], a[7]};
            if (nt) {
                __builtin_nontemporal_store(v0, (f32x4*)o);
                __builtin_nontemporal_store(v1, (f32x4*)(o + 4));
            } else {
                *(f32x4*)o = v0;
                *(f32x4*)(o + 4) = v1;
            }
        }
        if (out_bf) {
            uint4 pk;
            pk.x = pack2(a[0], a[1]); pk.y = pack2(a[2], a[3]);
            pk.z = pack2(a[4], a[5]); pk.w = pack2(a[6], a[7]);
            *(uint4*)(out_bf + ((size_t)seg << 6) + cc * 4) = pk;
        }
    }
}

// segment mean -> fp16 row (MLP input)
__device__ __forceinline__ void aggh_body(const u32* __restrict__ in,
                                          const int* __restrict__ items,
                                          const int* __restrict__ off,
                                          f16* __restrict__ outh,
                                          int nseg, int nrows, int seg) {
    if (seg >= nseg) return;
    float a[8];
    seg_mean8(in, items, off, nseg, nrows, seg, a);
    int lane = threadIdx.x & 63, rs = lane >> 4, cc = lane & 15;
    if (rs == 0) {
        union { f16 h[8]; uint4 v; } u;
#pragma unroll
        for (int i = 0; i < 8; ++i) u.h[i] = (f16)a[i];
        *(uint4*)(outh + ((size_t)seg << 7) + cc * 8) = u.v;
    }
}

// ---------- LDS-free single-product GEMM body: out (opt +=) A[M,128] @ WL[128,128] ----------
// WL is fp16 col-major linear: WL[c*128 + k]. A is f32 row-major. 32 rows per call.
__device__ __forceinline__ void gemm1_body(const float* __restrict__ A,
                                           const f16* __restrict__ WL,
                                           float* __restrict__ out, int M,
                                           int rb, int accum, int nt) {
    int t = threadIdx.x, lane = t & 63, wv = t >> 6;
    int r0 = (wv >> 1) << 4, ctb = (wv & 1) << 2;
    int frow = lane & 15, fk = (lane >> 4) << 3;
    int rl0 = r0 + ((lane >> 4) << 2);
    int ar = rb + r0 + frow;
    f32x4 acc[4];
#pragma unroll
    for (int j = 0; j < 4; ++j) {
        int c = ((ctb + j) << 4) + frow;
#pragma unroll
        for (int rg = 0; rg < 4; ++rg) {
            int row = rb + rl0 + rg;
            acc[j][rg] = (accum && row < M) ? out[((size_t)row << 7) + c] : 0.f;
        }
    }
#pragma unroll
    for (int ks = 0; ks < 4; ++ks) {
        int kb = ks * 32 + fk;
        half8 af;
        if (ar < M) {
            float4 a0 = *(const float4*)(A + ((size_t)ar << 7) + kb);
            float4 a1 = *(const float4*)(A + ((size_t)ar << 7) + kb + 4);
            af[0] = (f16)a0.x; af[1] = (f16)a0.y; af[2] = (f16)a0.z; af[3] = (f16)a0.w;
            af[4] = (f16)a1.x; af[5] = (f16)a1.y; af[6] = (f16)a1.z; af[7] = (f16)a1.w;
        } else {
#pragma unroll
            for (int j = 0; j < 8; ++j) af[j] = (f16)0.f;
        }
#pragma unroll
        for (int j = 0; j < 4; ++j) {
            int c = ((ctb + j) << 4) + frow;
            half8 bf = *(const half8*)(WL + ((size_t)c << 7) + kb);
            acc[j] = __builtin_amdgcn_mfma_f32_16x16x32_f16(af, bf, acc[j], 0, 0, 0);
        }
    }
#pragma unroll
    for (int j = 0; j < 4; ++j) {
        int c = ((ctb + j) << 4) + frow;
#pragma unroll
        for (int rg = 0; rg < 4; ++rg) {
            int row = rb + rl0 + rg;
            if (row < M) {
                if (nt) __builtin_nontemporal_store(acc[j][rg], out + ((size_t)row << 7) + c);
                else out[((size_t)row << 7) + c] = acc[j][rg];
            }
        }
    }
}

// ---------- front kernel: bucket hist + comp hist + wprep + (last-block) scan ----------
// blockIdx.x roles: [0,nbh) hist (+ticket), [nbh, nbh+64) wprep (6 swizzled + 2 linear).
__global__ __launch_bounds__(256) void k_front(
        const int* __restrict__ ni, const int* __restrict__ ei,
        const int* __restrict__ nc_c, const int* __restrict__ ec_c,
        int* __restrict__ bcntE, int* __restrict__ bcntN,
        int* __restrict__ cnt_cn, int* __restrict__ cnt_ce,
        int nnz, int n, int e, int nbh,
        int* __restrict__ ticket,
        int* __restrict__ basesE, int* __restrict__ basesN,
        int* __restrict__ bcur_e, int* __restrict__ bcur_n,
        int* __restrict__ off_cn, int* __restrict__ off_ce,
        int* __restrict__ cur_cn, int* __restrict__ cur_ce, int c,
        const float* __restrict__ W0, const float* __restrict__ W1,
        const float* __restrict__ W2, const float* __restrict__ W3,
        const float* __restrict__ W4, const float* __restrict__ W5,
        f16* __restrict__ wt6) {
    int t = threadIdx.x;
    int b = blockIdx.x;
    if (b >= nbh) {                        // ---- wprep blocks ----
        int gid = (b - nbh) * 256 + t;
        if (gid >= 8 * 2048) return;
        int m = gid >> 11;
        int rem = gid & 2047;
        int cq = rem >> 4;            // 0..127 (output col)
        int s = rem & 15;             // 16B slot within 256B row
        const float* W = (m == 0) ? W0 : (m == 1) ? W1 : (m == 2) ? W2 :
                         (m == 3) ? W3 : (m == 4) ? W4 : (m == 5) ? W5 :
                         (m == 6) ? W4 : W5;      // 6,7: linear copies of Wec1,Wnc1
        int khi = (m < 6) ? (((s & 7) ^ (cq & 7)) | (s & 8)) : s;   // swizzle inverse / linear
        int k0 = khi << 3;
        union { f16 h[8]; uint4 v; } u;
#pragma unroll
        for (int j = 0; j < 8; ++j) u.h[j] = (f16)W[((k0 + j) << 7) + cq];
        *(uint4*)(wt6 + ((size_t)m << 14) + (cq << 7) + (s << 3)) = u.v;
        return;
    }
    // ---- hist blocks ----
    __shared__ int hE[KB2], hN[KB2];
    __shared__ int lastflag;
    hE[t] = 0; hN[t] = 0;
    __syncthreads();
    int base = b * CH;
    int lim = base + CH; if (lim > nnz) lim = nnz;
    for (int i = base + t; i < lim; i += 256) {
        u32 v = (u32)ni[i], eg = (u32)ei[i];
        if (v >= (u32)n) v = 0;
        if (eg >= (u32)e) eg = 0;
        atomicAdd(&hE[(int)(((unsigned long long)eg * KB2) / (u32)e)], 1);
        atomicAdd(&hN[(int)(((unsigned long long)v  * KB2) / (u32)n)], 1);
    }
    __syncthreads();
    if (hE[t]) atomicAdd(&bcntE[t], hE[t]);
    if (hN[t]) atomicAdd(&bcntN[t], hN[t]);
    // comp histogram, grid-stride over hist blocks only
    int gid = b * 256 + t, stride = nbh * 256;
    for (int j = gid; j < n + e; j += stride) {
        if (j < n) atomicAdd(&cnt_cn[nc_c[j]], 1);
        else       atomicAdd(&cnt_ce[ec_c[j - n]], 1);
    }
    // last hist block to finish runs the scans
    __syncthreads();
    if (t == 0) {
        __threadfence();
        lastflag = (atomicAdd(ticket, 1) == nbh - 1);
    }
    __syncthreads();
    if (!lastflag) return;
    __threadfence();
    int tot;
    int v = bcntE[t];
    int ex = blk_exscan(v, tot);
    basesE[t] = ex; bcur_e[t] = ex;
    if (t == 0) basesE[KB2] = tot;
    v = bcntN[t];
    ex = blk_exscan(v, tot);
    basesN[t] = ex; bcur_n[t] = ex;
    if (t == 0) basesN[KB2] = tot;
    int i0 = 2 * t, i1 = 2 * t + 1;
    int v0 = (i0 < c) ? cnt_cn[i0] : 0;
    int v1 = (i1 < c) ? cnt_cn[i1] : 0;
    ex = blk_exscan(v0 + v1, tot);
    if (i0 < c) { off_cn[i0] = ex;      cur_cn[i0] = ex; }
    if (i1 < c) { off_cn[i1] = ex + v0; cur_cn[i1] = ex + v0; }
    if (t == 0) off_cn[c] = tot;
    v0 = (i0 < c) ? cnt_ce[i0] : 0;
    v1 = (i1 < c) ? cnt_ce[i1] : 0;
    ex = blk_exscan(v0 + v1, tot);
    if (i0 < c) { off_ce[i0] = ex;      cur_ce[i0] = ex; }
    if (i1 < c) { off_ce[i1] = ex + v0; cur_ce[i1] = ex + v0; }
    if (t == 0) off_ce[c] = tot;
}

// ---------- phase A: dual-side LDS radix partition (single edge read) + comp scatter + cvt ----------
// blockIdx.x roles: [0,nbh) partition BOTH sides for chunk b, [nbh, nbh+nkc) cvt blocks.
__global__ __launch_bounds__(256) void k_part_a(
        const int* __restrict__ ni, const int* __restrict__ ei,
        int* __restrict__ bcur_e, int* __restrict__ bcur_n,
        u32* __restrict__ stg_e, u32* __restrict__ stg_n,
        const int* __restrict__ nc_n, const int* __restrict__ nc_c,
        const int* __restrict__ ec_e, const int* __restrict__ ec_c,
        int* __restrict__ cur_cn, int* __restrict__ cur_ce,
        int* __restrict__ csr_cn, int* __restrict__ csr_ce,
        const float2* __restrict__ xin, u32* __restrict__ xout, int npairs,
        int nnz, int n, int e, int nbh) {
    int t = threadIdx.x;
    int bx = blockIdx.x;
    if (bx >= nbh) {                       // ---- cvt blocks ----
        int j = (bx - nbh) * 256 + t;
        if (j < npairs) { float2 v = xin[j]; xout[j] = pack2(v.x, v.y); }
        return;
    }
    __shared__ u32 pkE[CH];
    __shared__ u32 pkN[CH];
    __shared__ unsigned short bbE[CH];
    __shared__ unsigned short bbN[CH];
    __shared__ int histE[KB2], histN[KB2];
    __shared__ int gbE[KB2], gbN[KB2];
    int base = bx * CH;
    int cnt  = nnz - base; if (cnt > CH) cnt = CH;
    for (int i = t; i < KB2; i += 256) { histE[i] = 0; histN[i] = 0; }
    __syncthreads();
    for (int i = t; i < cnt; i += 256) {
        u32 v = (u32)ni[base + i], eg = (u32)ei[base + i];
        if (v >= (u32)n) v = 0;
        if (eg >= (u32)e) eg = 0;
        u32 bE = (u32)(((unsigned long long)eg * KB2) / (u32)e);
        u32 bN = (u32)(((unsigned long long)v  * KB2) / (u32)n);
        pkE[i] = v | (eg << 16);
        pkN[i] = eg | (v << 14);
        bbE[i] = (unsigned short)bE;
        bbN[i] = (unsigned short)bN;
        atomicAdd(&histE[bE], 1);
        atomicAdd(&histN[bN], 1);
    }
    __syncthreads();
    if (t < KB2) {
        int h = histE[t];
        gbE[t] = h ? atomicAdd(&bcur_e[t], h) : 0;
        histE[t] = 0;
        h = histN[t];
        gbN[t] = h ? atomicAdd(&bcur_n[t], h) : 0;
        histN[t] = 0;
    }
    __syncthreads();
    for (int i = t; i < cnt; i += 256) {
        int b = bbE[i];
        int r = atomicAdd(&histE[b], 1);
        stg_e[gbE[b] + r] = pkE[i];
        b = bbN[i];
        r = atomicAdd(&histN[b], 1);
        stg_n[gbN[b] + r] = pkN[i];
    }
    // fused component scatters (both sides), grid-stride over partition blocks
    int gid = bx * 256 + t;
    int stride = nbh * 256;
    for (int j = gid; j < e; j += stride) { int c = ec_c[j]; csr_ce[atomicAdd(&cur_ce[c], 1)] = ec_e[j]; }
    for (int j = gid; j < n; j += stride) { int c = nc_c[j]; csr_cn[atomicAdd(&cur_cn[c], 1)] = nc_n[j]; }
}

// ---------- phase B: per-bucket degree count + offsets + CSR scatter ----------
__global__ __launch_bounds__(256) void k_part_b2(
        const u32* __restrict__ stg_e, const u32* __restrict__ stg_n,
        const int* __restrict__ basesE, const int* __restrict__ basesN,
        int* __restrict__ off_e, int* __restrict__ off_n,
        int* __restrict__ csr_e, int* __restrict__ csr_n, int e, int n) {
    __shared__ int lcnt[256];
    int b = blockIdx.x, t = threadIdx.x;
    const u32* stg; const int* bases; int* off; int* csr; int total; int shift; u32 mask;
    if (b < KB2) { stg = stg_e; bases = basesE; off = off_e; csr = csr_e; total = e; shift = 16; mask = 0xFFFFu; }
    else { b -= KB2; stg = stg_n; bases = basesN; off = off_n; csr = csr_n; total = n; shift = 14; mask = 0x3FFFu; }
    int lo = bstart2(b, total), hi = bstart2(b + 1, total);
    int nid = hi - lo;
    int sbase = bases[b], send = bases[b + 1];
    lcnt[t] = 0;
    __syncthreads();
    for (int i = sbase + t; i < send; i += 256) {
        int key = (int)(stg[i] >> shift);
        atomicAdd(&lcnt[key - lo], 1);
    }
    __syncthreads();
    int cval = (t < nid) ? lcnt[t] : 0;
    int tot;
    int ex = blk_exscan(cval, tot);      // internal syncs protect lcnt reuse
    int cursor = sbase + ex;
    if (t < nid) { off[lo + t] = cursor; lcnt[t] = cursor; }
    if (t == 0 && hi == total) off[total] = send;
    __syncthreads();
    for (int i = sbase + t; i < send; i += 256) {
        u32 s = stg[i];
        int key = (int)(s >> shift);
        int pay = (int)(s & mask);
        int p = atomicAdd(&lcnt[key - lo], 1);
        csr[p] = pay;
    }
}

// ================= fallback path (generality guard; unused at these sizes) ========
__global__ void k_cvt(const float2* __restrict__ in, u32* __restrict__ out, int npairs) {
    int j = blockIdx.x * blockDim.x + threadIdx.x;
    if (j < npairs) { float2 v = in[j]; out[j] = pack2(v.x, v.y); }
}

__global__ void k_hist_fb(const int* __restrict__ ni, const int* __restrict__ ei,
                          const int* __restrict__ nc_c, const int* __restrict__ ec_c,
                          int* __restrict__ deg_e, int* __restrict__ deg_n,
                          int* __restrict__ cnt_cn, int* __restrict__ cnt_ce,
                          int nnz, int n, int e) {
    int j = blockIdx.x * blockDim.x + threadIdx.x;
    if (j < nnz) {
        atomicAdd(&deg_e[ei[j]], 1);
        atomicAdd(&deg_n[ni[j]], 1);
    }
    if (j < n) atomicAdd(&cnt_cn[nc_c[j]], 1);
    if (j < e) atomicAdd(&cnt_ce[ec_c[j]], 1);
}

__device__ __forceinline__ void scan_sel(int b, int t0, int t01, int t012,
        const int* c0, int* o0, int* u0, int n0,
        const int* c1, int* o1, int* u1, int n1,
        const int* c2, int* o2, int* u2, int n2,
        const int* c3, int* o3, int* u3, int n3,
        const int*& cnt, int*& off, int*& cur, int& n, int& tile) {
    if (b < t0)        { cnt = c0; off = o0; cur = u0; n = n0; tile = b; }
    else if (b < t01)  { cnt = c1; off = o1; cur = u1; n = n1; tile = b - t0; }
    else if (b < t012) { cnt = c2; off = o2; cur = u2; n = n2; tile = b - t01; }
    else               { cnt = c3; off = o3; cur = u3; n = n3; tile = b - t012; }
}

__global__ void k_scan_p1(const int* c0, int n0, const int* c1, int n1,
                          const int* c2, int n2, const int* c3, int n3,
                          int t0, int t01, int t012, int* __restrict__ tilesum) {
    __shared__ int ws[4];
    int b = blockIdx.x;
    const int* cnt; int* off; int* cur; int n; int tile;
    scan_sel(b, t0, t01, t012, c0, nullptr, nullptr, n0, c1, nullptr, nullptr, n1,
             c2, nullptr, nullptr, n2, c3, nullptr, nullptr, n3, cnt, off, cur, n, tile);
    int base = tile * TS + threadIdx.x * 16;
    int s = 0;
#pragma unroll
    for (int i = 0; i < 16; ++i) { int idx = base + i; if (idx < n) s += cnt[idx]; }
    for (int d = 32; d; d >>= 1) s += __shfl_xor(s, d, 64);
    int lane = threadIdx.x & 63, w = threadIdx.x >> 6;
    if (lane == 0) ws[w] = s;
    __syncthreads();
    if (threadIdx.x == 0) tilesum[b] = ws[0] + ws[1] + ws[2] + ws[3];
}

__global__ void k_scan_p2(const int* __restrict__ tilesum, int* __restrict__ tilebase,
                          int t0, int t01, int t012, int t0123,
                          int* o0, int n0, int* o1, int n1, int* o2, int n2, int* o3, int n3) {
    if (threadIdx.x != 0 || blockIdx.x != 0) return;
    int carry = 0;
    for (int b = 0;    b < t0;    ++b) { tilebase[b] = carry; carry += tilesum[b]; } o0[n0] = carry;
    carry = 0;
    for (int b = t0;   b < t01;   ++b) { tilebase[b] = carry; carry += tilesum[b]; } o1[n1] = carry;
    carry = 0;
    for (int b = t01;  b < t012;  ++b) { tilebase[b] = carry; carry += tilesum[b]; } o2[n2] = carry;
    carry = 0;
    for (int b = t012; b < t0123; ++b) { tilebase[b] = carry; carry += tilesum[b]; } o3[n3] = carry;
}

__global__ void k_scan_p3(const int* c0, int* o0, int* u0, int n0,
                          const int* c1, int* o1, int* u1, int n1,
                          const int* c2, int* o2, int* u2, int n2,
                          const int* c3, int* o3, int* u3, int n3,
                          int t0, int t01, int t012, const int* __restrict__ tilebase) {
    __shared__ int wsum[4];
    int b = blockIdx.x;
    const int* cnt; int* off; int* cur; int n; int tile;
    scan_sel(b, t0, t01, t012, c0, o0, u0, n0, c1, o1, u1, n1,
             c2, o2, u2, n2, c3, o3, u3, n3, cnt, off, cur, n, tile);
    int lane = threadIdx.x & 63, w = threadIdx.x >> 6;
    int base = tile * TS + threadIdx.x * 16;
    int vals[16];
    int s = 0;
#pragma unroll
    for (int i = 0; i < 16; ++i) { int idx = base + i; int v = (idx < n) ? cnt[idx] : 0; vals[i] = v; s += v; }
    int inc = s;
    for (int d = 1; d < 64; d <<= 1) { int u = __shfl_up(inc, d, 64); if (lane >= d) inc += u; }
    if (lane == 63) wsum[w] = inc;
    __syncthreads();
    if (threadIdx.x == 0) {
        int acc = tilebase[b];
        for (int i = 0; i < 4; ++i) { int t = wsum[i]; wsum[i] = acc; acc += t; }
    }
    __syncthreads();
    int ex = wsum[w] + (inc - s);
#pragma unroll
    for (int i = 0; i < 16; ++i) {
        int idx = base + i;
        if (idx < n) { off[idx] = ex; cur[idx] = ex; }
        ex += vals[i];
    }
}

__global__ void k_scatter(const int* __restrict__ ni, const int* __restrict__ ei,
                          const int* __restrict__ nc_n, const int* __restrict__ nc_c,
                          const int* __restrict__ ec_e, const int* __restrict__ ec_c,
                          int* __restrict__ cur_e, int* __restrict__ cur_n,
                          int* __restrict__ cur_cn, int* __restrict__ cur_ce,
                          int* __restrict__ csr_e, int* __restrict__ csr_n,
                          int* __restrict__ csr_cn, int* __restrict__ csr_ce,
                          int nnz, int n, int e) {
    int j = blockIdx.x * blockDim.x + threadIdx.x;
    if (j < nnz) {
        int v = ni[j], eg = ei[j];
        csr_e[atomicAdd(&cur_e[eg], 1)] = v;
        csr_n[atomicAdd(&cur_n[v], 1)] = eg;
    }
    if (j < n) { int c = nc_c[j]; csr_cn[atomicAdd(&cur_cn[c], 1)] = nc_n[j]; }
    if (j < e) { int c = ec_c[j]; csr_ce[atomicAdd(&cur_ce[c], 1)] = ec_e[j]; }
}
// ================= end fallback =================

__global__ __launch_bounds__(256) void k_agg4(
        const u32* __restrict__ in, const int* __restrict__ items,
        const int* __restrict__ off, float* __restrict__ out_f32,
        u32* __restrict__ out_bf,
        int nseg, int nrows, int do_prelu, const float* __restrict__ alpha_p) {
    int seg = blockIdx.x * (blockDim.x >> 6) + (threadIdx.x >> 6);
    agg4_body(in, items, off, out_f32, out_bf, nseg, nrows, do_prelu, alpha_p, seg, 0);
}

// ---------- segment mean -> fp16 rows (MLP input) ----------
__global__ __launch_bounds__(256) void k_agg4h(
        const u32* __restrict__ in, const int* __restrict__ items,
        const int* __restrict__ off, f16* __restrict__ outh,
        int nseg, int nrows) {
    int seg = blockIdx.x * (blockDim.x >> 6) + (threadIdx.x >> 6);
    aggh_body(in, items, off, outh, nseg, nrows, seg);
}

// ---------- final aggregation dispatch: node output + ce comp mean + gemm_n ----------
// blocks: [0,nblkN) N-agg->out_x(NT); [nblkN,nblkN+ncb) ce-agg->ca_e;
//         [nblkN+ncb, +gc) out_c = ca_n @ WncL (LDS-free MFMA; ca_n from prev dispatch)
__global__ __launch_bounds__(256) void k_agg_final(
        const u32* __restrict__ ybf, const int* __restrict__ csr_n, const int* __restrict__ off_n,
        float* __restrict__ out_x, int n, int e,
        const u32* __restrict__ eactbf, const int* __restrict__ csr_ce, const int* __restrict__ off_ce,
        float* __restrict__ ca_e,
        const float* __restrict__ ca_n, const f16* __restrict__ WncL,
        float* __restrict__ out_c,
        int c, int nblkN, int ncb, const float* __restrict__ alpha_p) {
    int b = blockIdx.x;
    int wv = threadIdx.x >> 6;
    if (b < nblkN) {
        agg4_body(ybf, csr_n, off_n, out_x, nullptr, n, e, 1, alpha_p, b * 4 + wv, 1);
    } else if (b < nblkN + ncb) {
        agg4_body(eactbf, csr_ce, off_ce, ca_e, nullptr, c, e, 0, nullptr, (b - nblkN) * 4 + wv, 0);
    } else {
        gemm1_body(ca_n, WncL, out_c, c, (b - nblkN - ncb) * 32, 0, 0);
    }
}

// ---------- tail: out_c += ca_e @ WecL ----------
__global__ __launch_bounds__(256) void k_gemm1(
        const float* __restrict__ A, const f16* __restrict__ WL,
        float* __restrict__ out, int M) {
    gemm1_body(A, WL, out, M, blockIdx.x * 32, 1, 1);
}

// ---------- fused 2-layer MLP via MFMA (fp16 global A in, fp32 accum) ----------
// 32 rows/block, 4 waves. LDS: As 8KB + Wt 32KB. Blocks >= nmlp run cn comp agg
// (independent gather work that fills idle CUs during the small MLP grid).
__global__ __launch_bounds__(256) void k_mlp_mfma(
        const f16* __restrict__ Ah,
        const f16* __restrict__ W1t, const f16* __restrict__ W2t,
        float* __restrict__ out_raw, u32* __restrict__ out_actbf,
        u32* __restrict__ out_ybf, int M, const float* __restrict__ alpha_p,
        int nmlp,
        const u32* __restrict__ cn_in, const int* __restrict__ cn_items,
        const int* __restrict__ cn_off, float* __restrict__ cn_out,
        int cn_nseg, int cn_nrows) {
    __shared__ f16 As[32 * 128];
    __shared__ f16 Wt[128 * 128];
    int t = threadIdx.x;
    if (blockIdx.x >= nmlp) {              // ---- cn component agg blocks ----
        if (cn_out == nullptr) return;
        int seg = (blockIdx.x - nmlp) * 4 + (t >> 6);
        agg4_body(cn_in, cn_items, cn_off, cn_out, nullptr, cn_nseg, cn_nrows, 0,
                  alpha_p, seg, 0);
        return;
    }
    int rb = blockIdx.x * 32;
    float al = *alpha_p;
    {   // Wt <- W1t (linear copy, already fp16+swizzled)
        const uint4* src = (const uint4*)W1t;
        uint4* dst = (uint4*)Wt;
        for (int i = t; i < 2048; i += 256) dst[i] = src[i];
    }
    // As <- Ah (fp16 rows, swizzle on LDS store)
    {
        const uint4* Ag = (const uint4*)Ah;
        for (int i = t; i < 512; i += 256) {
            int r = i >> 4, s = i & 15;
            int row = rb + r;
            uint4 v = make_uint4(0u, 0u, 0u, 0u);
            if (row < M) v = Ag[(size_t)row * 16 + s];
            *(uint4*)((char*)As + (r << 8) + ((s << 4) ^ ((r & 7) << 4))) = v;
        }
    }
    __syncthreads();

    int lane = t & 63, wv = t >> 6;
    int r0  = (wv >> 1) << 4;          // local row base 0/16
    int ctb = (wv & 1) << 2;           // col-tile base 0/4
    int frow = lane & 15;
    int fk = (lane >> 4) << 3;         // k sub-offset 0/8/16/24
    int rl0 = r0 + ((lane >> 4) << 2); // D-frag local row base
    int ar = r0 + frow;
    int asw = (ar & 7) << 4;

    f32x4 acc[4] = {{0.f,0.f,0.f,0.f},{0.f,0.f,0.f,0.f},{0.f,0.f,0.f,0.f},{0.f,0.f,0.f,0.f}};
#pragma unroll
    for (int ks = 0; ks < 4; ++ks) {
        int kb2 = (ks * 32 + fk) << 1;
        half8 a = *(const half8*)((const char*)As + (ar << 8) + (kb2 ^ asw));
#pragma unroll
        for (int j = 0; j < 4; ++j) {
            int c = ((ctb + j) << 4) + frow;
            half8 b = *(const half8*)((const char*)Wt + (c << 8) + (kb2 ^ ((c & 7) << 4)));
            acc[j] = __builtin_amdgcn_mfma_f32_16x16x32_f16(a, b, acc[j], 0, 0, 0);
        }
    }
    __syncthreads();                   // all mm1 LDS reads done
    {   // Wt <- W2t (issue early, overlaps epilogue)
        const uint4* src = (const uint4*)W2t;
        uint4* dst = (uint4*)Wt;
        for (int i = t; i < 2048; i += 256) dst[i] = src[i];
    }
    // epilogue mm1: raw e store (NT), prelu, actbf store, act -> As (fp16)
#pragma unroll
    for (int j = 0; j < 4; ++j) {
        int c = ((ctb + j) << 4) + frow;
#pragma unroll
        for (int rg = 0; rg < 4; ++rg) {
            int rl = rl0 + rg;
            int row = rb + rl;
            float ev = acc[j][rg];
            if (out_raw != nullptr && row < M)
                __builtin_nontemporal_store(ev, out_raw + ((size_t)row << 7) + c);
            float av = (ev >= 0.f) ? ev : al * ev;
            float po = __shfl_xor(av, 1, 64);
            if (out_actbf != nullptr && (frow & 1) == 0 && row < M)
                out_actbf[((size_t)row << 6) + (c >> 1)] = pack2(av, po);
            *(f16*)((char*)As + (rl << 8) + (((c << 1)) ^ ((rl & 7) << 4))) = (f16)av;
        }
    }
    __syncthreads();                   // act + W2t visible
    f32x4 acc2[4] = {{0.f,0.f,0.f,0.f},{0.f,0.f,0.f,0.f},{0.f,0.f,0.f,0.f},{0.f,0.f,0.f,0.f}};
#pragma unroll
    for (int ks = 0; ks < 4; ++ks) {
        int kb2 = (ks * 32 + fk) << 1;
        half8 a = *(const half8*)((const char*)As + (ar << 8) + (kb2 ^ asw));
#pragma unroll
        for (int j = 0; j < 4; ++j) {
            int c = ((ctb + j) << 4) + frow;
            half8 b = *(const half8*)((const char*)Wt + (c << 8) + (kb2 ^ ((c & 7) << 4)));
            acc2[j] = __builtin_amdgcn_mfma_f32_16x16x32_f16(a, b, acc2[j], 0, 0, 0);
        }
    }
#pragma unroll
    for (int j = 0; j < 4; ++j) {
        int c = ((ctb + j) << 4) + frow;
#pragma unroll
        for (int rg = 0; rg < 4; ++rg) {
            int rl = rl0 + rg;
            int row = rb + rl;
            float yv = acc2[j][rg];
            float po = __shfl_xor(yv, 1, 64);
            if ((frow & 1) == 0 && row < M)
                out_ybf[((size_t)row << 6) + (c >> 1)] = pack2(yv, po);
        }
    }
}

extern "C" void kernel_launch(void* const* d_in, const int* in_sizes, int n_in,
                              void* d_out, int out_size, void* d_ws, size_t ws_size,
                              hipStream_t stream) {
    const int N   = in_sizes[0] / 128;   // 50000
    const int NNZ = in_sizes[1] / 2;     // 400000
    const int E   = in_sizes[2] / 2;     // 10000
    const int C   = 500;

    const float* x0 = (const float*)d_in[0];
    const int* ni   = (const int*)d_in[1];
    const int* ei   = ni + NNZ;
    const int* ec_e = (const int*)d_in[2];
    const int* ec_c = ec_e + E;
    const int* nc_n = (const int*)d_in[3];
    const int* nc_c = nc_n + N;
    const float* Wne0 = (const float*)d_in[7];
    const float* Wen0 = (const float*)d_in[8];
    const float* Wne1 = (const float*)d_in[11];
    const float* Wen1 = (const float*)d_in[12];
    const float* Wec1 = (const float*)d_in[13];
    const float* Wnc1 = (const float*)d_in[14];
    const float* alpha = (const float*)d_in[15];

    float* out_x = (float*)d_out;                 // [N,128]
    float* out_e = out_x + (size_t)N * 128;       // [E,128]
    float* out_c = out_e + (size_t)E * 128;       // [C,128]

    // ---- carve workspace ----
    char* w = (char*)d_ws;
    auto alloc = [&](size_t bytes) { char* p = w; w += (bytes + 255) & ~(size_t)255; return p; };
    // zero-init group: bcntE | bcntN | cnt_cn | cnt_ce | ticket
    int* zgrp   = (int*)alloc((size_t)(2 * KB2 + 2 * C + 1) * 4);
    int* bcntE  = zgrp;
    int* bcntN  = zgrp + KB2;
    int* cnt_cn = zgrp + 2 * KB2;
    int* cnt_ce = zgrp + 2 * KB2 + C;
    int* ticket = zgrp + 2 * KB2 + 2 * C;
    int* off_e  = (int*)alloc((size_t)(E + 1) * 4);
    int* off_n  = (int*)alloc((size_t)(N + 1) * 4);
    int* off_cn = (int*)alloc((size_t)(C + 1) * 4);
    int* off_ce = (int*)alloc((size_t)(C + 1) * 4);
    int* cur_cn = (int*)alloc((size_t)C * 4);
    int* cur_ce = (int*)alloc((size_t)C * 4);
    int* csr_e  = (int*)alloc((size_t)NNZ * 4);
    int* csr_n  = (int*)alloc((size_t)NNZ * 4);
    int* csr_cn = (int*)alloc((size_t)N * 4);
    int* csr_ce = (int*)alloc((size_t)E * 4);
    int* basesE = (int*)alloc((size_t)(KB2 + 1) * 4);
    int* basesN = (int*)alloc((size_t)(KB2 + 1) * 4);
    int* bcur_e = (int*)alloc(KB2 * 4);
    int* bcur_n = (int*)alloc(KB2 * 4);
    u32* stg_e  = (u32*)alloc((size_t)NNZ * 4);
    u32* stg_n  = (u32*)alloc((size_t)NNZ * 4);
    u32* xbf    = (u32*)alloc((size_t)N * 64 * 4);
    u32* x1bf   = (u32*)alloc((size_t)N * 64 * 4);
    u32* ybf    = (u32*)alloc((size_t)E * 64 * 4);
    u32* eactbf = (u32*)alloc((size_t)E * 64 * 4);
    f16* xah    = (f16*)alloc((size_t)E * 128 * 2);     // E-agg fp16 output
    float* ca_e = (float*)alloc((size_t)C * 128 * 4);
    float* ca_n = (float*)alloc((size_t)C * 128 * 4);
    f16* wt6    = (f16*)alloc((size_t)8 * 16384 * 2);   // 6 swizzled + 2 linear fp16 weights
    // fallback-only buffers
    int* deg_e    = (int*)alloc((size_t)E * 4);
    int* deg_n    = (int*)alloc((size_t)N * 4);
    int* cur_e    = (int*)alloc((size_t)E * 4);
    int* cur_n    = (int*)alloc((size_t)N * 4);
    int* tilesum  = (int*)alloc(64 * 4);
    int* tilebase = (int*)alloc(64 * 4);

    const int th = 256;
    const int npairs = N * 64;
    const int nbh = (NNZ + CH - 1) / CH;
    const int nkc = (npairs + th - 1) / th;

    bool binned = (E <= 16384) && (N <= 65536) && (E >= KB2) && (N >= KB2) &&
                  ((N + KB2 - 1) / KB2 <= 256) && (C <= 512);
    const int nbh_eff = binned ? nbh : 0;

    hipMemsetAsync(zgrp, 0, (size_t)(2 * KB2 + 2 * C + 1) * 4, stream);
    // front: (binned) bucket/comp hist + last-block scan + wprep (8 matrices)
    k_front<<<nbh_eff + 64, 256, 0, stream>>>(
        ni, ei, nc_c, ec_c,
        bcntE, bcntN, cnt_cn, cnt_ce, NNZ, N, E, nbh_eff,
        ticket, basesE, basesN, bcur_e, bcur_n,
        off_cn, off_ce, cur_cn, cur_ce, C,
        Wne0, Wen0, Wne1, Wen1, Wec1, Wnc1, wt6);

    if (binned) {
        // dual-side partition (nbh blocks) + overlapped cvt (nkc blocks)
        k_part_a<<<nbh + nkc, 256, 0, stream>>>(
            ni, ei, bcur_e, bcur_n, stg_e, stg_n,
            nc_n, nc_c, ec_e, ec_c,
            cur_cn, cur_ce, csr_cn, csr_ce,
            (const float2*)x0, xbf, npairs, NNZ, N, E, nbh);
        k_part_b2<<<2 * KB2, 256, 0, stream>>>(stg_e, stg_n, basesE, basesN,
                                               off_e, off_n, csr_e, csr_n, E, N);
    } else {
        hipMemsetAsync(deg_e, 0, (size_t)E * 4, stream);
        hipMemsetAsync(deg_n, 0, (size_t)N * 4, stream);
        k_cvt<<<(npairs + th - 1) / th, th, 0, stream>>>((const float2*)x0, xbf, npairs);
        k_hist_fb<<<(NNZ > N + E ? NNZ : N + E) / th + 1, th, 0, stream>>>(
            ni, ei, nc_c, ec_c, deg_e, deg_n, cnt_cn, cnt_ce, NNZ, N, E);
        const int t0 = (E + TS - 1) / TS, t1 = (N + TS - 1) / TS;
        const int t2 = (C + TS - 1) / TS, t3 = (C + TS - 1) / TS;
        const int t01 = t0 + t1, t012 = t01 + t2, t0123 = t012 + t3;
        k_scan_p1<<<t0123, 256, 0, stream>>>(deg_e, E, deg_n, N, cnt_cn, C, cnt_ce, C,
                                             t0, t01, t012, tilesum);
        k_scan_p2<<<1, 64, 0, stream>>>(tilesum, tilebase, t0, t01, t012, t0123,
                                        off_e, E, off_n, N, off_cn, C, off_ce, C);
        k_scan_p3<<<t0123, 256, 0, stream>>>(deg_e, off_e, cur_e, E,
                                             deg_n, off_n, cur_n, N,
                                             cnt_cn, off_cn, cur_cn, C,
                                             cnt_ce, off_ce, cur_ce, C,
                                             t0, t01, t012, tilebase);
        k_scatter<<<(NNZ + th - 1) / th, th, 0, stream>>>(ni, ei, nc_n, nc_c, ec_e, ec_c,
                                                          cur_e, cur_n, cur_cn, cur_ce,
                                                          csr_e, csr_n, csr_cn, csr_ce, NNZ, N, E);
    }

    const int gmlp = (E + 31) / 32;
    const int ncb  = (C + 3) / 4;
    const int gc   = (C + 31) / 32;
    // ---- layer 1 ----
    k_agg4h<<<(E + 3) / 4, 256, 0, stream>>>(xbf, csr_e, off_e, xah, E, N);
    k_mlp_mfma<<<gmlp, 256, 0, stream>>>(xah, wt6, wt6 + 16384, nullptr, nullptr, ybf,
                                         E, alpha, gmlp,
                                         nullptr, nullptr, nullptr, nullptr, 0, 0);
    k_agg4<<<(N + 3) / 4, 256, 0, stream>>>(ybf, csr_n, off_n, nullptr, x1bf, N, E, 1, alpha);
    // ---- layer 2 ----
    k_agg4h<<<(E + 3) / 4, 256, 0, stream>>>(x1bf, csr_e, off_e, xah, E, N);
    // MLP L2 + overlapped cn-component agg (needs only x1bf)
    k_mlp_mfma<<<gmlp + ncb, 256, 0, stream>>>(xah, wt6 + 2 * 16384, wt6 + 3 * 16384,
                                               out_e, eactbf, ybf, E, alpha, gmlp,
                                               x1bf, csr_cn, off_cn, ca_n, C, N);
    // ---- final: node output agg + ce comp agg + gemm_n (out_c = ca_n @ WncL) ----
    {
        const int nblkN = (N + 3) / 4;
        k_agg_final<<<nblkN + ncb + gc, 256, 0, stream>>>(
            ybf, csr_n, off_n, out_x, N, E,
            eactbf, csr_ce, off_ce, ca_e,
            ca_n, wt6 + 7 * 16384, out_c,
            C, nblkN, ncb, alpha);
    }
    // ---- tail: out_c += ca_e @ WecL ----
    k_gemm1<<<gc, 256, 0, stream>>>(ca_e, wt6 + 6 * 16384, out_c, C);
}

// Round 7
// 254.750 us; speedup vs baseline: 1.0591x; 1.0591x over previous
//
#include <hip/hip_runtime.h>
#include <stdint.h>

typedef unsigned int u32;
typedef _Float16 f16;
typedef f16 half8 __attribute__((ext_vector_type(8)));
typedef float f32x4 __attribute__((ext_vector_type(4)));
#define TS 4096     // scan tile size (fallback path)
#define KB2 256     // partition buckets per side
#define CH 2048     // entries per phase-A / bhist block

// ---------- bf16 helpers ----------
__device__ __forceinline__ float bflo(u32 u) { return __uint_as_float(u << 16); }
__device__ __forceinline__ float bfhi(u32 u) { return __uint_as_float(u & 0xffff0000u); }
__device__ __forceinline__ u32 f2bf(float x) {
    u32 u = __float_as_uint(x);
    return (u + 0x7fffu + ((u >> 16) & 1u)) >> 16;   // RNE
}
__device__ __forceinline__ u32 pack2(float a, float b) { return f2bf(a) | (f2bf(b) << 16); }

__device__ __forceinline__ int bstart2(int b, int total) {
    return (int)(((unsigned long long)b * (u32)total + KB2 - 1) / KB2);
}

// block-wide exclusive scan, 256 threads, one value per thread
__device__ __forceinline__ int blk_exscan(int v, int& total) {
    __shared__ int ws[5];
    int t = threadIdx.x, lane = t & 63, w = t >> 6;
    int inc = v;
    for (int d = 1; d < 64; d <<= 1) { int u = __shfl_up(inc, d, 64); if (lane >= d) inc += u; }
    __syncthreads();                    // protect ws across repeated calls
    if (lane == 63) ws[w] = inc;
    __syncthreads();
    if (t == 0) { int acc = 0; for (int i = 0; i < 4; ++i) { int x = ws[i]; ws[i] = acc; acc += x; } ws[4] = acc; }
    __syncthreads();
    total = ws[4];
    return ws[w] + (inc - v);
}

// ---------- segment mean core: per-wave, 4 row-slots x 16 chunk-lanes ----------
#define ACC8(v) do { \
    a[0] += bflo((v).x); a[1] += bfhi((v).x); a[2] += bflo((v).y); a[3] += bfhi((v).y); \
    a[4] += bflo((v).z); a[5] += bfhi((v).z); a[6] += bflo((v).w); a[7] += bfhi((v).w); } while (0)

__device__ __forceinline__ void seg_mean8(const u32* __restrict__ in,
                                          const int* __restrict__ items,
                                          const int* __restrict__ off,
                                          int nseg, int nrows, int seg, float a[8]) {
    int lane = threadIdx.x & 63;
    int rs = lane >> 4;
    int cc = lane & 15;
#pragma unroll
    for (int i = 0; i < 8; ++i) a[i] = 0.f;
    int s0 = 0, s1 = 0;
    if (seg < nseg) { s0 = off[seg]; s1 = off[seg + 1]; }
    const uint4* rows = (const uint4*)in;
    int base = s0;
    // 16-wide: 4 gathers (4 KB) in flight per wave
    for (; base + 16 <= s1; base += 16) {
        u32 r0 = (u32)items[base + rs];
        u32 r1 = (u32)items[base + 4 + rs];
        u32 r2 = (u32)items[base + 8 + rs];
        u32 r3 = (u32)items[base + 12 + rs];
        r0 = (r0 < (u32)nrows) ? r0 : 0u;
        r1 = (r1 < (u32)nrows) ? r1 : 0u;
        r2 = (r2 < (u32)nrows) ? r2 : 0u;
        r3 = (r3 < (u32)nrows) ? r3 : 0u;
        uint4 v0 = rows[(size_t)r0 * 16 + cc];
        uint4 v1 = rows[(size_t)r1 * 16 + cc];
        uint4 v2 = rows[(size_t)r2 * 16 + cc];
        uint4 v3 = rows[(size_t)r3 * 16 + cc];
        ACC8(v0); ACC8(v1); ACC8(v2); ACC8(v3);
    }
    for (; base + 8 <= s1; base += 8) {
        u32 r0 = (u32)items[base + rs];
        u32 r1 = (u32)items[base + 4 + rs];
        r0 = (r0 < (u32)nrows) ? r0 : 0u;
        r1 = (r1 < (u32)nrows) ? r1 : 0u;
        uint4 v0 = rows[(size_t)r0 * 16 + cc];
        uint4 v1 = rows[(size_t)r1 * 16 + cc];
        ACC8(v0); ACC8(v1);
    }
    int idx = base + rs;
    if (idx < s1) {
        u32 r = (u32)items[idx]; r = (r < (u32)nrows) ? r : 0u;
        uint4 v = rows[(size_t)r * 16 + cc];
        ACC8(v);
    }
    idx += 4;
    if (idx < s1) {
        u32 r = (u32)items[idx]; r = (r < (u32)nrows) ? r : 0u;
        uint4 v = rows[(size_t)r * 16 + cc];
        ACC8(v);
    }
#pragma unroll
    for (int i = 0; i < 8; ++i) {
        a[i] += __shfl_xor(a[i], 16, 64);
        a[i] += __shfl_xor(a[i], 32, 64);
    }
    float inv = 1.f / fmaxf((float)(s1 - s0), 1.f);
#pragma unroll
    for (int i = 0; i < 8; ++i) a[i] *= inv;
}

__device__ __forceinline__ void agg4_body(const u32* __restrict__ in,
                                          const int* __restrict__ items,
                                          const int* __restrict__ off,
                                          float* __restrict__ out_f32,
                                          u32* __restrict__ out_bf,
                                          int nseg, int nrows, int do_prelu,
                                          const float* __restrict__ alpha_p, int seg,
                                          int nt) {
    if (seg >= nseg) return;
    int lane = threadIdx.x & 63;
    int rs = lane >> 4;
    int cc = lane & 15;
    float a[8];
    seg_mean8(in, items, off, nseg, nrows, seg, a);
    if (do_prelu) {
        float al = *alpha_p;
#pragma unroll
        for (int i = 0; i < 8; ++i) a[i] = (a[i] >= 0.f) ? a[i] : al * a[i];
    }
    if (rs == 0) {
        if (out_f32) {
            float* o = out_f32 + ((size_t)seg << 7) + cc * 8;
            f32x4 v0 = {a[0], a[1], a[2], a[3]};
            f32x4 v1 = {a[4], a[5], a[6], a[7]};
            if (nt) {
                __builtin_nontemporal_store(v0, (f32x4*)o);
                __builtin_nontemporal_store(v1, (f32x4*)(o + 4));
            } else {
                *(f32x4*)o = v0;
                *(f32x4*)(o + 4) = v1;
            }
        }
        if (out_bf) {
            uint4 pk;
            pk.x = pack2(a[0], a[1]); pk.y = pack2(a[2], a[3]);
            pk.z = pack2(a[4], a[5]); pk.w = pack2(a[6], a[7]);
            *(uint4*)(out_bf + ((size_t)seg << 6) + cc * 4) = pk;
        }
    }
}

// segment mean -> fp16 row (MLP input)
__device__ __forceinline__ void aggh_body(const u32* __restrict__ in,
                                          const int* __restrict__ items,
                                          const int* __restrict__ off,
                                          f16* __restrict__ outh,
                                          int nseg, int nrows, int seg) {
    if (seg >= nseg) return;
    float a[8];
    seg_mean8(in, items, off, nseg, nrows, seg, a);
    int lane = threadIdx.x & 63, rs = lane >> 4, cc = lane & 15;
    if (rs == 0) {
        union { f16 h[8]; uint4 v; } u;
#pragma unroll
        for (int i = 0; i < 8; ++i) u.h[i] = (f16)a[i];
        *(uint4*)(outh + ((size_t)seg << 7) + cc * 8) = u.v;
    }
}

// ---------- LDS-free single-product GEMM body: out (opt +=) A[M,128] @ WL[128,128] ----------
// WL is fp16 col-major linear: WL[c*128 + k]. A is f32 row-major. 32 rows per call.
__device__ __forceinline__ void gemm1_body(const float* __restrict__ A,
                                           const f16* __restrict__ WL,
                                           float* __restrict__ out, int M,
                                           int rb, int accum, int nt) {
    int t = threadIdx.x, lane = t & 63, wv = t >> 6;
    int r0 = (wv >> 1) << 4, ctb = (wv & 1) << 2;
    int frow = lane & 15, fk = (lane >> 4) << 3;
    int rl0 = r0 + ((lane >> 4) << 2);
    int ar = rb + r0 + frow;
    f32x4 acc[4];
#pragma unroll
    for (int j = 0; j < 4; ++j) {
        int c = ((ctb + j) << 4) + frow;
#pragma unroll
        for (int rg = 0; rg < 4; ++rg) {
            int row = rb + rl0 + rg;
            acc[j][rg] = (accum && row < M) ? out[((size_t)row << 7) + c] : 0.f;
        }
    }
#pragma unroll
    for (int ks = 0; ks < 4; ++ks) {
        int kb = ks * 32 + fk;
        half8 af;
        if (ar < M) {
            float4 a0 = *(const float4*)(A + ((size_t)ar << 7) + kb);
            float4 a1 = *(const float4*)(A + ((size_t)ar << 7) + kb + 4);
            af[0] = (f16)a0.x; af[1] = (f16)a0.y; af[2] = (f16)a0.z; af[3] = (f16)a0.w;
            af[4] = (f16)a1.x; af[5] = (f16)a1.y; af[6] = (f16)a1.z; af[7] = (f16)a1.w;
        } else {
#pragma unroll
            for (int j = 0; j < 8; ++j) af[j] = (f16)0.f;
        }
#pragma unroll
        for (int j = 0; j < 4; ++j) {
            int c = ((ctb + j) << 4) + frow;
            half8 bf = *(const half8*)(WL + ((size_t)c << 7) + kb);
            acc[j] = __builtin_amdgcn_mfma_f32_16x16x32_f16(af, bf, acc[j], 0, 0, 0);
        }
    }
#pragma unroll
    for (int j = 0; j < 4; ++j) {
        int c = ((ctb + j) << 4) + frow;
#pragma unroll
        for (int rg = 0; rg < 4; ++rg) {
            int row = rb + rl0 + rg;
            if (row < M) {
                if (nt) __builtin_nontemporal_store(acc[j][rg], out + ((size_t)row << 7) + c);
                else out[((size_t)row << 7) + c] = acc[j][rg];
            }
        }
    }
}

// ---------- front kernel: bucket hist + comp hist + wprep + (last-block) scan ----------
// blockIdx.x roles: [0,nbh) hist (+ticket), [nbh, nbh+64) wprep (6 swizzled + 2 linear).
__global__ __launch_bounds__(256) void k_front(
        const int* __restrict__ ni, const int* __restrict__ ei,
        const int* __restrict__ nc_c, const int* __restrict__ ec_c,
        int* __restrict__ bcntE, int* __restrict__ bcntN,
        int* __restrict__ cnt_cn, int* __restrict__ cnt_ce,
        int nnz, int n, int e, int nbh,
        int* __restrict__ ticket,
        int* __restrict__ basesE, int* __restrict__ basesN,
        int* __restrict__ bcur_e, int* __restrict__ bcur_n,
        int* __restrict__ off_cn, int* __restrict__ off_ce,
        int* __restrict__ cur_cn, int* __restrict__ cur_ce, int c,
        const float* __restrict__ W0, const float* __restrict__ W1,
        const float* __restrict__ W2, const float* __restrict__ W3,
        const float* __restrict__ W4, const float* __restrict__ W5,
        f16* __restrict__ wt6) {
    int t = threadIdx.x;
    int b = blockIdx.x;
    if (b >= nbh) {                        // ---- wprep blocks ----
        int gid = (b - nbh) * 256 + t;
        if (gid >= 8 * 2048) return;
        int m = gid >> 11;
        int rem = gid & 2047;
        int cq = rem >> 4;            // 0..127 (output col)
        int s = rem & 15;             // 16B slot within 256B row
        const float* W = (m == 0) ? W0 : (m == 1) ? W1 : (m == 2) ? W2 :
                         (m == 3) ? W3 : (m == 4) ? W4 : (m == 5) ? W5 :
                         (m == 6) ? W4 : W5;      // 6,7: linear copies of Wec1,Wnc1
        int khi = (m < 6) ? (((s & 7) ^ (cq & 7)) | (s & 8)) : s;   // swizzle inverse / linear
        int k0 = khi << 3;
        union { f16 h[8]; uint4 v; } u;
#pragma unroll
        for (int j = 0; j < 8; ++j) u.h[j] = (f16)W[((k0 + j) << 7) + cq];
        *(uint4*)(wt6 + ((size_t)m << 14) + (cq << 7) + (s << 3)) = u.v;
        return;
    }
    // ---- hist blocks ----
    __shared__ int hE[KB2], hN[KB2];
    __shared__ int lastflag;
    hE[t] = 0; hN[t] = 0;
    __syncthreads();
    int base = b * CH;
    int lim = base + CH; if (lim > nnz) lim = nnz;
    for (int i = base + t; i < lim; i += 256) {
        u32 v = (u32)ni[i], eg = (u32)ei[i];
        if (v >= (u32)n) v = 0;
        if (eg >= (u32)e) eg = 0;
        atomicAdd(&hE[(int)(((unsigned long long)eg * KB2) / (u32)e)], 1);
        atomicAdd(&hN[(int)(((unsigned long long)v  * KB2) / (u32)n)], 1);
    }
    __syncthreads();
    if (hE[t]) atomicAdd(&bcntE[t], hE[t]);
    if (hN[t]) atomicAdd(&bcntN[t], hN[t]);
    // comp histogram, grid-stride over hist blocks only
    int gid = b * 256 + t, stride = nbh * 256;
    for (int j = gid; j < n + e; j += stride) {
        if (j < n) atomicAdd(&cnt_cn[nc_c[j]], 1);
        else       atomicAdd(&cnt_ce[ec_c[j - n]], 1);
    }
    // last hist block to finish runs the scans
    __syncthreads();
    if (t == 0) {
        __threadfence();
        lastflag = (atomicAdd(ticket, 1) == nbh - 1);
    }
    __syncthreads();
    if (!lastflag) return;
    __threadfence();
    int tot;
    int v = bcntE[t];
    int ex = blk_exscan(v, tot);
    basesE[t] = ex; bcur_e[t] = ex;
    if (t == 0) basesE[KB2] = tot;
    v = bcntN[t];
    ex = blk_exscan(v, tot);
    basesN[t] = ex; bcur_n[t] = ex;
    if (t == 0) basesN[KB2] = tot;
    int i0 = 2 * t, i1 = 2 * t + 1;
    int v0 = (i0 < c) ? cnt_cn[i0] : 0;
    int v1 = (i1 < c) ? cnt_cn[i1] : 0;
    ex = blk_exscan(v0 + v1, tot);
    if (i0 < c) { off_cn[i0] = ex;      cur_cn[i0] = ex; }
    if (i1 < c) { off_cn[i1] = ex + v0; cur_cn[i1] = ex + v0; }
    if (t == 0) off_cn[c] = tot;
    v0 = (i0 < c) ? cnt_ce[i0] : 0;
    v1 = (i1 < c) ? cnt_ce[i1] : 0;
    ex = blk_exscan(v0 + v1, tot);
    if (i0 < c) { off_ce[i0] = ex;      cur_ce[i0] = ex; }
    if (i1 < c) { off_ce[i1] = ex + v0; cur_ce[i1] = ex + v0; }
    if (t == 0) off_ce[c] = tot;
}

// ---------- phase A: LDS radix partition + fused comp scatter + fused x->bf16 cvt ----------
__global__ __launch_bounds__(256) void k_part_a(
        const int* __restrict__ ni, const int* __restrict__ ei,
        int* __restrict__ bcur_e, int* __restrict__ bcur_n,
        u32* __restrict__ stg_e, u32* __restrict__ stg_n,
        const int* __restrict__ nc_n, const int* __restrict__ nc_c,
        const int* __restrict__ ec_e, const int* __restrict__ ec_c,
        int* __restrict__ cur_cn, int* __restrict__ cur_ce,
        int* __restrict__ csr_cn, int* __restrict__ csr_ce,
        const float2* __restrict__ xin, u32* __restrict__ xout, int npairs,
        int nnz, int n, int e, int nbh) {
    __shared__ u32 pk[CH];
    __shared__ unsigned short bb[CH];
    __shared__ int hist[KB2];
    __shared__ int gb[KB2];
    int t = threadIdx.x;
    int bx = blockIdx.x;
    if (bx >= 2 * nbh) {                   // ---- cvt blocks ----
        int j = (bx - 2 * nbh) * 256 + t;
        if (j < npairs) { float2 v = xin[j]; xout[j] = pack2(v.x, v.y); }
        return;
    }
    int side = bx >= nbh;
    int pb = side ? bx - nbh : bx;
    int base = pb * CH;
    int cnt  = nnz - base; if (cnt > CH) cnt = CH;
    for (int i = t; i < KB2; i += 256) hist[i] = 0;
    __syncthreads();
    u32 total = side ? (u32)n : (u32)e;
    for (int i = t; i < cnt; i += 256) {
        int v = ni[base + i], eg = ei[base + i];
        u32 key = side ? (u32)v : (u32)eg;
        u32 pay = side ? (u32)eg : (u32)v;
        if (key >= total) key = 0;
        u32 b = (u32)(((unsigned long long)key * KB2) / total);
        pk[i] = side ? (pay | (key << 14)) : (pay | (key << 16));
        bb[i] = (unsigned short)b;
        atomicAdd(&hist[b], 1);
    }
    __syncthreads();
    int* cursor = side ? bcur_n : bcur_e;
    u32* stg    = side ? stg_n  : stg_e;
    if (t < KB2) {
        int h = hist[t];
        gb[t] = h ? atomicAdd(&cursor[t], h) : 0;
        hist[t] = 0;
    }
    __syncthreads();
    for (int i = t; i < cnt; i += 256) {
        int b = bb[i];
        int r = atomicAdd(&hist[b], 1);
        stg[gb[b] + r] = pk[i];
    }
    // fused component scatter: side 0 -> edges, side 1 -> nodes
    int gid = pb * 256 + t;
    int stride = nbh * 256;
    if (side == 0) {
        for (int j = gid; j < e; j += stride) { int c = ec_c[j]; csr_ce[atomicAdd(&cur_ce[c], 1)] = ec_e[j]; }
    } else {
        for (int j = gid; j < n; j += stride) { int c = nc_c[j]; csr_cn[atomicAdd(&cur_cn[c], 1)] = nc_n[j]; }
    }
}

// ---------- phase B: per-bucket degree count + offsets + CSR scatter ----------
__global__ __launch_bounds__(256) void k_part_b2(
        const u32* __restrict__ stg_e, const u32* __restrict__ stg_n,
        const int* __restrict__ basesE, const int* __restrict__ basesN,
        int* __restrict__ off_e, int* __restrict__ off_n,
        int* __restrict__ csr_e, int* __restrict__ csr_n, int e, int n) {
    __shared__ int lcnt[256];
    int b = blockIdx.x, t = threadIdx.x;
    const u32* stg; const int* bases; int* off; int* csr; int total; int shift; u32 mask;
    if (b < KB2) { stg = stg_e; bases = basesE; off = off_e; csr = csr_e; total = e; shift = 16; mask = 0xFFFFu; }
    else { b -= KB2; stg = stg_n; bases = basesN; off = off_n; csr = csr_n; total = n; shift = 14; mask = 0x3FFFu; }
    int lo = bstart2(b, total), hi = bstart2(b + 1, total);
    int nid = hi - lo;
    int sbase = bases[b], send = bases[b + 1];
    lcnt[t] = 0;
    __syncthreads();
    for (int i = sbase + t; i < send; i += 256) {
        int key = (int)(stg[i] >> shift);
        atomicAdd(&lcnt[key - lo], 1);
    }
    __syncthreads();
    int cval = (t < nid) ? lcnt[t] : 0;
    int tot;
    int ex = blk_exscan(cval, tot);      // internal syncs protect lcnt reuse
    int cursor = sbase + ex;
    if (t < nid) { off[lo + t] = cursor; lcnt[t] = cursor; }
    if (t == 0 && hi == total) off[total] = send;
    __syncthreads();
    for (int i = sbase + t; i < send; i += 256) {
        u32 s = stg[i];
        int key = (int)(s >> shift);
        int pay = (int)(s & mask);
        int p = atomicAdd(&lcnt[key - lo], 1);
        csr[p] = pay;
    }
}

// ================= fallback path (generality guard; unused at these sizes) ========
__global__ void k_cvt(const float2* __restrict__ in, u32* __restrict__ out, int npairs) {
    int j = blockIdx.x * blockDim.x + threadIdx.x;
    if (j < npairs) { float2 v = in[j]; out[j] = pack2(v.x, v.y); }
}

__global__ void k_hist_fb(const int* __restrict__ ni, const int* __restrict__ ei,
                          const int* __restrict__ nc_c, const int* __restrict__ ec_c,
                          int* __restrict__ deg_e, int* __restrict__ deg_n,
                          int* __restrict__ cnt_cn, int* __restrict__ cnt_ce,
                          int nnz, int n, int e) {
    int j = blockIdx.x * blockDim.x + threadIdx.x;
    if (j < nnz) {
        atomicAdd(&deg_e[ei[j]], 1);
        atomicAdd(&deg_n[ni[j]], 1);
    }
    if (j < n) atomicAdd(&cnt_cn[nc_c[j]], 1);
    if (j < e) atomicAdd(&cnt_ce[ec_c[j]], 1);
}

__device__ __forceinline__ void scan_sel(int b, int t0, int t01, int t012,
        const int* c0, int* o0, int* u0, int n0,
        const int* c1, int* o1, int* u1, int n1,
        const int* c2, int* o2, int* u2, int n2,
        const int* c3, int* o3, int* u3, int n3,
        const int*& cnt, int*& off, int*& cur, int& n, int& tile) {
    if (b < t0)        { cnt = c0; off = o0; cur = u0; n = n0; tile = b; }
    else if (b < t01)  { cnt = c1; off = o1; cur = u1; n = n1; tile = b - t0; }
    else if (b < t012) { cnt = c2; off = o2; cur = u2; n = n2; tile = b - t01; }
    else               { cnt = c3; off = o3; cur = u3; n = n3; tile = b - t012; }
}

__global__ void k_scan_p1(const int* c0, int n0, const int* c1, int n1,
                          const int* c2, int n2, const int* c3, int n3,
                          int t0, int t01, int t012, int* __restrict__ tilesum) {
    __shared__ int ws[4];
    int b = blockIdx.x;
    const int* cnt; int* off; int* cur; int n; int tile;
    scan_sel(b, t0, t01, t012, c0, nullptr, nullptr, n0, c1, nullptr, nullptr, n1,
             c2, nullptr, nullptr, n2, c3, nullptr, nullptr, n3, cnt, off, cur, n, tile);
    int base = tile * TS + threadIdx.x * 16;
    int s = 0;
#pragma unroll
    for (int i = 0; i < 16; ++i) { int idx = base + i; if (idx < n) s += cnt[idx]; }
    for (int d = 32; d; d >>= 1) s += __shfl_xor(s, d, 64);
    int lane = threadIdx.x & 63, w = threadIdx.x >> 6;
    if (lane == 0) ws[w] = s;
    __syncthreads();
    if (threadIdx.x == 0) tilesum[b] = ws[0] + ws[1] + ws[2] + ws[3];
}

__global__ void k_scan_p2(const int* __restrict__ tilesum, int* __restrict__ tilebase,
                          int t0, int t01, int t012, int t0123,
                          int* o0, int n0, int* o1, int n1, int* o2, int n2, int* o3, int n3) {
    if (threadIdx.x != 0 || blockIdx.x != 0) return;
    int carry = 0;
    for (int b = 0;    b < t0;    ++b) { tilebase[b] = carry; carry += tilesum[b]; } o0[n0] = carry;
    carry = 0;
    for (int b = t0;   b < t01;   ++b) { tilebase[b] = carry; carry += tilesum[b]; } o1[n1] = carry;
    carry = 0;
    for (int b = t01;  b < t012;  ++b) { tilebase[b] = carry; carry += tilesum[b]; } o2[n2] = carry;
    carry = 0;
    for (int b = t012; b < t0123; ++b) { tilebase[b] = carry; carry += tilesum[b]; } o3[n3] = carry;
}

__global__ void k_scan_p3(const int* c0, int* o0, int* u0, int n0,
                          const int* c1, int* o1, int* u1, int n1,
                          const int* c2, int* o2, int* u2, int n2,
                          const int* c3, int* o3, int* u3, int n3,
                          int t0, int t01, int t012, const int* __restrict__ tilebase) {
    __shared__ int wsum[4];
    int b = blockIdx.x;
    const int* cnt; int* off; int* cur; int n; int tile;
    scan_sel(b, t0, t01, t012, c0, o0, u0, n0, c1, o1, u1, n1,
             c2, o2, u2, n2, c3, o3, u3, n3, cnt, off, cur, n, tile);
    int lane = threadIdx.x & 63, w = threadIdx.x >> 6;
    int base = tile * TS + threadIdx.x * 16;
    int vals[16];
    int s = 0;
#pragma unroll
    for (int i = 0; i < 16; ++i) { int idx = base + i; int v = (idx < n) ? cnt[idx] : 0; vals[i] = v; s += v; }
    int inc = s;
    for (int d = 1; d < 64; d <<= 1) { int u = __shfl_up(inc, d, 64); if (lane >= d) inc += u; }
    if (lane == 63) wsum[w] = inc;
    __syncthreads();
    if (threadIdx.x == 0) {
        int acc = tilebase[b];
        for (int i = 0; i < 4; ++i) { int t = wsum[i]; wsum[i] = acc; acc += t; }
    }
    __syncthreads();
    int ex = wsum[w] + (inc - s);
#pragma unroll
    for (int i = 0; i < 16; ++i) {
        int idx = base + i;
        if (idx < n) { off[idx] = ex; cur[idx] = ex; }
        ex += vals[i];
    }
}

__global__ void k_scatter(const int* __restrict__ ni, const int* __restrict__ ei,
                          const int* __restrict__ nc_n, const int* __restrict__ nc_c,
                          const int* __restrict__ ec_e, const int* __restrict__ ec_c,
                          int* __restrict__ cur_e, int* __restrict__ cur_n,
                          int* __restrict__ cur_cn, int* __restrict__ cur_ce,
                          int* __restrict__ csr_e, int* __restrict__ csr_n,
                          int* __restrict__ csr_cn, int* __restrict__ csr_ce,
                          int nnz, int n, int e) {
    int j = blockIdx.x * blockDim.x + threadIdx.x;
    if (j < nnz) {
        int v = ni[j], eg = ei[j];
        csr_e[atomicAdd(&cur_e[eg], 1)] = v;
        csr_n[atomicAdd(&cur_n[v], 1)] = eg;
    }
    if (j < n) { int c = nc_c[j]; csr_cn[atomicAdd(&cur_cn[c], 1)] = nc_n[j]; }
    if (j < e) { int c = ec_c[j]; csr_ce[atomicAdd(&cur_ce[c], 1)] = ec_e[j]; }
}
// ================= end fallback =================

__global__ __launch_bounds__(256) void k_agg4(
        const u32* __restrict__ in, const int* __restrict__ items,
        const int* __restrict__ off, float* __restrict__ out_f32,
        u32* __restrict__ out_bf,
        int nseg, int nrows, int do_prelu, const float* __restrict__ alpha_p) {
    int seg = blockIdx.x * (blockDim.x >> 6) + (threadIdx.x >> 6);
    agg4_body(in, items, off, out_f32, out_bf, nseg, nrows, do_prelu, alpha_p, seg, 0);
}

// ---------- segment mean -> fp16 rows (MLP input) ----------
__global__ __launch_bounds__(256) void k_agg4h(
        const u32* __restrict__ in, const int* __restrict__ items,
        const int* __restrict__ off, f16* __restrict__ outh,
        int nseg, int nrows) {
    int seg = blockIdx.x * (blockDim.x >> 6) + (threadIdx.x >> 6);
    aggh_body(in, items, off, outh, nseg, nrows, seg);
}

// ---------- final aggregation dispatch: node output + ce comp mean + gemm_n ----------
// blocks: [0,nblkN) N-agg->out_x(NT); [nblkN,nblkN+ncb) ce-agg->ca_e;
//         [nblkN+ncb, +gc) out_c = ca_n @ WncL (LDS-free MFMA; ca_n from prev dispatch)
__global__ __launch_bounds__(256) void k_agg_final(
        const u32* __restrict__ ybf, const int* __restrict__ csr_n, const int* __restrict__ off_n,
        float* __restrict__ out_x, int n, int e,
        const u32* __restrict__ eactbf, const int* __restrict__ csr_ce, const int* __restrict__ off_ce,
        float* __restrict__ ca_e,
        const float* __restrict__ ca_n, const f16* __restrict__ WncL,
        float* __restrict__ out_c,
        int c, int nblkN, int ncb, const float* __restrict__ alpha_p) {
    int b = blockIdx.x;
    int wv = threadIdx.x >> 6;
    if (b < nblkN) {
        agg4_body(ybf, csr_n, off_n, out_x, nullptr, n, e, 1, alpha_p, b * 4 + wv, 1);
    } else if (b < nblkN + ncb) {
        agg4_body(eactbf, csr_ce, off_ce, ca_e, nullptr, c, e, 0, nullptr, (b - nblkN) * 4 + wv, 0);
    } else {
        gemm1_body(ca_n, WncL, out_c, c, (b - nblkN - ncb) * 32, 0, 0);
    }
}

// ---------- tail: out_c += ca_e @ WecL ----------
__global__ __launch_bounds__(256) void k_gemm1(
        const float* __restrict__ A, const f16* __restrict__ WL,
        float* __restrict__ out, int M) {
    gemm1_body(A, WL, out, M, blockIdx.x * 32, 1, 1);
}

// ---------- fused 2-layer MLP via MFMA (fp16 global A in, fp32 accum) ----------
// 32 rows/block, 4 waves. LDS: As 8KB + Wt 32KB. Blocks >= nmlp run cn comp agg
// (independent gather work that fills idle CUs during the small MLP grid).
__global__ __launch_bounds__(256) void k_mlp_mfma(
        const f16* __restrict__ Ah,
        const f16* __restrict__ W1t, const f16* __restrict__ W2t,
        float* __restrict__ out_raw, u32* __restrict__ out_actbf,
        u32* __restrict__ out_ybf, int M, const float* __restrict__ alpha_p,
        int nmlp,
        const u32* __restrict__ cn_in, const int* __restrict__ cn_items,
        const int* __restrict__ cn_off, float* __restrict__ cn_out,
        int cn_nseg, int cn_nrows) {
    __shared__ f16 As[32 * 128];
    __shared__ f16 Wt[128 * 128];
    int t = threadIdx.x;
    if (blockIdx.x >= nmlp) {              // ---- cn component agg blocks ----
        if (cn_out == nullptr) return;
        int seg = (blockIdx.x - nmlp) * 4 + (t >> 6);
        agg4_body(cn_in, cn_items, cn_off, cn_out, nullptr, cn_nseg, cn_nrows, 0,
                  alpha_p, seg, 0);
        return;
    }
    int rb = blockIdx.x * 32;
    float al = *alpha_p;
    {   // Wt <- W1t (linear copy, already fp16+swizzled)
        const uint4* src = (const uint4*)W1t;
        uint4* dst = (uint4*)Wt;
        for (int i = t; i < 2048; i += 256) dst[i] = src[i];
    }
    // As <- Ah (fp16 rows, swizzle on LDS store)
    {
        const uint4* Ag = (const uint4*)Ah;
        for (int i = t; i < 512; i += 256) {
            int r = i >> 4, s = i & 15;
            int row = rb + r;
            uint4 v = make_uint4(0u, 0u, 0u, 0u);
            if (row < M) v = Ag[(size_t)row * 16 + s];
            *(uint4*)((char*)As + (r << 8) + ((s << 4) ^ ((r & 7) << 4))) = v;
        }
    }
    __syncthreads();

    int lane = t & 63, wv = t >> 6;
    int r0  = (wv >> 1) << 4;          // local row base 0/16
    int ctb = (wv & 1) << 2;           // col-tile base 0/4
    int frow = lane & 15;
    int fk = (lane >> 4) << 3;         // k sub-offset 0/8/16/24
    int rl0 = r0 + ((lane >> 4) << 2); // D-frag local row base
    int ar = r0 + frow;
    int asw = (ar & 7) << 4;

    f32x4 acc[4] = {{0.f,0.f,0.f,0.f},{0.f,0.f,0.f,0.f},{0.f,0.f,0.f,0.f},{0.f,0.f,0.f,0.f}};
#pragma unroll
    for (int ks = 0; ks < 4; ++ks) {
        int kb2 = (ks * 32 + fk) << 1;
        half8 a = *(const half8*)((const char*)As + (ar << 8) + (kb2 ^ asw));
#pragma unroll
        for (int j = 0; j < 4; ++j) {
            int c = ((ctb + j) << 4) + frow;
            half8 b = *(const half8*)((const char*)Wt + (c << 8) + (kb2 ^ ((c & 7) << 4)));
            acc[j] = __builtin_amdgcn_mfma_f32_16x16x32_f16(a, b, acc[j], 0, 0, 0);
        }
    }
    __syncthreads();                   // all mm1 LDS reads done
    {   // Wt <- W2t (issue early, overlaps epilogue)
        const uint4* src = (const uint4*)W2t;
        uint4* dst = (uint4*)Wt;
        for (int i = t; i < 2048; i += 256) dst[i] = src[i];
    }
    // epilogue mm1: raw e store (NT), prelu, actbf store, act -> As (fp16)
#pragma unroll
    for (int j = 0; j < 4; ++j) {
        int c = ((ctb + j) << 4) + frow;
#pragma unroll
        for (int rg = 0; rg < 4; ++rg) {
            int rl = rl0 + rg;
            int row = rb + rl;
            float ev = acc[j][rg];
            if (out_raw != nullptr && row < M)
                __builtin_nontemporal_store(ev, out_raw + ((size_t)row << 7) + c);
            float av = (ev >= 0.f) ? ev : al * ev;
            float po = __shfl_xor(av, 1, 64);
            if (out_actbf != nullptr && (frow & 1) == 0 && row < M)
                out_actbf[((size_t)row << 6) + (c >> 1)] = pack2(av, po);
            *(f16*)((char*)As + (rl << 8) + (((c << 1)) ^ ((rl & 7) << 4))) = (f16)av;
        }
    }
    __syncthreads();                   // act + W2t visible
    f32x4 acc2[4] = {{0.f,0.f,0.f,0.f},{0.f,0.f,0.f,0.f},{0.f,0.f,0.f,0.f},{0.f,0.f,0.f,0.f}};
#pragma unroll
    for (int ks = 0; ks < 4; ++ks) {
        int kb2 = (ks * 32 + fk) << 1;
        half8 a = *(const half8*)((const char*)As + (ar << 8) + (kb2 ^ asw));
#pragma unroll
        for (int j = 0; j < 4; ++j) {
            int c = ((ctb + j) << 4) + frow;
            half8 b = *(const half8*)((const char*)Wt + (c << 8) + (kb2 ^ ((c & 7) << 4)));
            acc2[j] = __builtin_amdgcn_mfma_f32_16x16x32_f16(a, b, acc2[j], 0, 0, 0);
        }
    }
#pragma unroll
    for (int j = 0; j < 4; ++j) {
        int c = ((ctb + j) << 4) + frow;
#pragma unroll
        for (int rg = 0; rg < 4; ++rg) {
            int rl = rl0 + rg;
            int row = rb + rl;
            float yv = acc2[j][rg];
            float po = __shfl_xor(yv, 1, 64);
            if ((frow & 1) == 0 && row < M)
                out_ybf[((size_t)row << 6) + (c >> 1)] = pack2(yv, po);
        }
    }
}

extern "C" void kernel_launch(void* const* d_in, const int* in_sizes, int n_in,
                              void* d_out, int out_size, void* d_ws, size_t ws_size,
                              hipStream_t stream) {
    const int N   = in_sizes[0] / 128;   // 50000
    const int NNZ = in_sizes[1] / 2;     // 400000
    const int E   = in_sizes[2] / 2;     // 10000
    const int C   = 500;

    const float* x0 = (const float*)d_in[0];
    const int* ni   = (const int*)d_in[1];
    const int* ei   = ni + NNZ;
    const int* ec_e = (const int*)d_in[2];
    const int* ec_c = ec_e + E;
    const int* nc_n = (const int*)d_in[3];
    const int* nc_c = nc_n + N;
    const float* Wne0 = (const float*)d_in[7];
    const float* Wen0 = (const float*)d_in[8];
    const float* Wne1 = (const float*)d_in[11];
    const float* Wen1 = (const float*)d_in[12];
    const float* Wec1 = (const float*)d_in[13];
    const float* Wnc1 = (const float*)d_in[14];
    const float* alpha = (const float*)d_in[15];

    float* out_x = (float*)d_out;                 // [N,128]
    float* out_e = out_x + (size_t)N * 128;       // [E,128]
    float* out_c = out_e + (size_t)E * 128;       // [C,128]

    // ---- carve workspace ----
    char* w = (char*)d_ws;
    auto alloc = [&](size_t bytes) { char* p = w; w += (bytes + 255) & ~(size_t)255; return p; };
    // zero-init group: bcntE | bcntN | cnt_cn | cnt_ce | ticket
    int* zgrp   = (int*)alloc((size_t)(2 * KB2 + 2 * C + 1) * 4);
    int* bcntE  = zgrp;
    int* bcntN  = zgrp + KB2;
    int* cnt_cn = zgrp + 2 * KB2;
    int* cnt_ce = zgrp + 2 * KB2 + C;
    int* ticket = zgrp + 2 * KB2 + 2 * C;
    int* off_e  = (int*)alloc((size_t)(E + 1) * 4);
    int* off_n  = (int*)alloc((size_t)(N + 1) * 4);
    int* off_cn = (int*)alloc((size_t)(C + 1) * 4);
    int* off_ce = (int*)alloc((size_t)(C + 1) * 4);
    int* cur_cn = (int*)alloc((size_t)C * 4);
    int* cur_ce = (int*)alloc((size_t)C * 4);
    int* csr_e  = (int*)alloc((size_t)NNZ * 4);
    int* csr_n  = (int*)alloc((size_t)NNZ * 4);
    int* csr_cn = (int*)alloc((size_t)N * 4);
    int* csr_ce = (int*)alloc((size_t)E * 4);
    int* basesE = (int*)alloc((size_t)(KB2 + 1) * 4);
    int* basesN = (int*)alloc((size_t)(KB2 + 1) * 4);
    int* bcur_e = (int*)alloc(KB2 * 4);
    int* bcur_n = (int*)alloc(KB2 * 4);
    u32* stg_e  = (u32*)alloc((size_t)NNZ * 4);
    u32* stg_n  = (u32*)alloc((size_t)NNZ * 4);
    u32* xbf    = (u32*)alloc((size_t)N * 64 * 4);
    u32* x1bf   = (u32*)alloc((size_t)N * 64 * 4);
    u32* ybf    = (u32*)alloc((size_t)E * 64 * 4);
    u32* eactbf = (u32*)alloc((size_t)E * 64 * 4);
    f16* xah    = (f16*)alloc((size_t)E * 128 * 2);     // E-agg fp16 output
    float* ca_e = (float*)alloc((size_t)C * 128 * 4);
    float* ca_n = (float*)alloc((size_t)C * 128 * 4);
    f16* wt6    = (f16*)alloc((size_t)8 * 16384 * 2);   // 6 swizzled + 2 linear fp16 weights
    // fallback-only buffers
    int* deg_e    = (int*)alloc((size_t)E * 4);
    int* deg_n    = (int*)alloc((size_t)N * 4);
    int* cur_e    = (int*)alloc((size_t)E * 4);
    int* cur_n    = (int*)alloc((size_t)N * 4);
    int* tilesum  = (int*)alloc(64 * 4);
    int* tilebase = (int*)alloc(64 * 4);

    const int th = 256;
    const int npairs = N * 64;
    const int nbh = (NNZ + CH - 1) / CH;
    const int nkc = (npairs + th - 1) / th;

    bool binned = (E <= 16384) && (N <= 65536) && (E >= KB2) && (N >= KB2) &&
                  ((N + KB2 - 1) / KB2 <= 256) && (C <= 512);
    const int nbh_eff = binned ? nbh : 0;

    hipMemsetAsync(zgrp, 0, (size_t)(2 * KB2 + 2 * C + 1) * 4, stream);
    // front: (binned) bucket/comp hist + last-block scan + wprep (8 matrices)
    k_front<<<nbh_eff + 64, 256, 0, stream>>>(
        ni, ei, nc_c, ec_c,
        bcntE, bcntN, cnt_cn, cnt_ce, NNZ, N, E, nbh_eff,
        ticket, basesE, basesN, bcur_e, bcur_n,
        off_cn, off_ce, cur_cn, cur_ce, C,
        Wne0, Wen0, Wne1, Wen1, Wec1, Wnc1, wt6);

    if (binned) {
        // partition (2*nbh blocks) + overlapped cvt (nkc blocks)
        k_part_a<<<2 * nbh + nkc, 256, 0, stream>>>(
            ni, ei, bcur_e, bcur_n, stg_e, stg_n,
            nc_n, nc_c, ec_e, ec_c,
            cur_cn, cur_ce, csr_cn, csr_ce,
            (const float2*)x0, xbf, npairs, NNZ, N, E, nbh);
        k_part_b2<<<2 * KB2, 256, 0, stream>>>(stg_e, stg_n, basesE, basesN,
                                               off_e, off_n, csr_e, csr_n, E, N);
    } else {
        hipMemsetAsync(deg_e, 0, (size_t)E * 4, stream);
        hipMemsetAsync(deg_n, 0, (size_t)N * 4, stream);
        k_cvt<<<(npairs + th - 1) / th, th, 0, stream>>>((const float2*)x0, xbf, npairs);
        k_hist_fb<<<(NNZ > N + E ? NNZ : N + E) / th + 1, th, 0, stream>>>(
            ni, ei, nc_c, ec_c, deg_e, deg_n, cnt_cn, cnt_ce, NNZ, N, E);
        const int t0 = (E + TS - 1) / TS, t1 = (N + TS - 1) / TS;
        const int t2 = (C + TS - 1) / TS, t3 = (C + TS - 1) / TS;
        const int t01 = t0 + t1, t012 = t01 + t2, t0123 = t012 + t3;
        k_scan_p1<<<t0123, 256, 0, stream>>>(deg_e, E, deg_n, N, cnt_cn, C, cnt_ce, C,
                                             t0, t01, t012, tilesum);
        k_scan_p2<<<1, 64, 0, stream>>>(tilesum, tilebase, t0, t01, t012, t0123,
                                        off_e, E, off_n, N, off_cn, C, off_ce, C);
        k_scan_p3<<<t0123, 256, 0, stream>>>(deg_e, off_e, cur_e, E,
                                             deg_n, off_n, cur_n, N,
                                             cnt_cn, off_cn, cur_cn, C,
                                             cnt_ce, off_ce, cur_ce, C,
                                             t0, t01, t012, tilebase);
        k_scatter<<<(NNZ + th - 1) / th, th, 0, stream>>>(ni, ei, nc_n, nc_c, ec_e, ec_c,
                                                          cur_e, cur_n, cur_cn, cur_ce,
                                                          csr_e, csr_n, csr_cn, csr_ce, NNZ, N, E);
    }

    const int gmlp = (E + 31) / 32;
    const int ncb  = (C + 3) / 4;
    const int gc   = (C + 31) / 32;
    // ---- layer 1 ----
    k_agg4h<<<(E + 3) / 4, 256, 0, stream>>>(xbf, csr_e, off_e, xah, E, N);
    k_mlp_mfma<<<gmlp, 256, 0, stream>>>(xah, wt6, wt6 + 16384, nullptr, nullptr, ybf,
                                         E, alpha, gmlp,
                                         nullptr, nullptr, nullptr, nullptr, 0, 0);
    k_agg4<<<(N + 3) / 4, 256, 0, stream>>>(ybf, csr_n, off_n, nullptr, x1bf, N, E, 1, alpha);
    // ---- layer 2 ----
    k_agg4h<<<(E + 3) / 4, 256, 0, stream>>>(x1bf, csr_e, off_e, xah, E, N);
    // MLP L2 + overlapped cn-component agg (needs only x1bf)
    k_mlp_mfma<<<gmlp + ncb, 256, 0, stream>>>(xah, wt6 + 2 * 16384, wt6 + 3 * 16384,
                                               out_e, eactbf, ybf, E, alpha, gmlp,
                                               x1bf, csr_cn, off_cn, ca_n, C, N);
    // ---- final: node output agg + ce comp agg + gemm_n (out_c = ca_n @ WncL) ----
    {
        const int nblkN = (N + 3) / 4;
        k_agg_final<<<nblkN + ncb + gc, 256, 0, stream>>>(
            ybf, csr_n, off_n, out_x, N, E,
            eactbf, csr_ce, off_ce, ca_e,
            ca_n, wt6 + 7 * 16384, out_c,
            C, nblkN, ncb, alpha);
    }
    // ---- tail: out_c += ca_e @ WecL ----
    k_gemm1<<<gc, 256, 0, stream>>>(ca_e, wt6 + 6 * 16384, out_c, C);
}